// Round 1
// baseline (670.296 us; speedup 1.0000x reference)
//
#include <hip/hip_runtime.h>
#include <math.h>

static constexpr int IMG = 784;      // 28*28
static constexpr int NQ = 7;         // mse, ssim, so, st, soo, stt, sot
static constexpr int NBUCKET = 256;

// Gaussian window WIN=11, SIGMA=1.5, normalized (precomputed in double).
__device__ constexpr float GW[11] = {
  0.00102838f, 0.00759875f, 0.03600077f, 0.10936070f, 0.21300554f,
  0.26601173f, 0.21300554f, 0.10936070f, 0.03600077f, 0.00759875f, 0.00102838f
};

// order-preserving float <-> uint map (for atomic min/max on floats)
__device__ __forceinline__ unsigned fmap(float f) {
  unsigned b = __float_as_uint(f);
  return (b & 0x80000000u) ? ~b : (b | 0x80000000u);
}
__device__ __forceinline__ float funmap(unsigned u) {
  unsigned b = (u & 0x80000000u) ? (u & 0x7fffffffu) : ~u;
  return __uint_as_float(b);
}

// ws layout (32-bit words): [0]=min_u, [1]=max_u, [2 .. 2+NQ*NBUCKET) = float buckets
__global__ __launch_bounds__(256) void init_kernel(unsigned* __restrict__ w) {
  int idx = blockIdx.x * blockDim.x + threadIdx.x;
  if (idx < 2 + NQ * NBUCKET) w[idx] = (idx == 0) ? 0xFFFFFFFFu : 0u;
}

__global__ __launch_bounds__(256) void minmax_kernel(const float4* __restrict__ t,
                                                     int n4, unsigned* __restrict__ w) {
  float lmin = 3.402823466e38f, lmax = -3.402823466e38f;
  const int stride = gridDim.x * blockDim.x;
  for (int i = blockIdx.x * blockDim.x + threadIdx.x; i < n4; i += stride) {
    const float4 x = t[i];
    lmin = fminf(lmin, fminf(fminf(x.x, x.y), fminf(x.z, x.w)));
    lmax = fmaxf(lmax, fmaxf(fmaxf(x.x, x.y), fmaxf(x.z, x.w)));
  }
  #pragma unroll
  for (int off = 32; off > 0; off >>= 1) {
    lmin = fminf(lmin, __shfl_down(lmin, off));
    lmax = fmaxf(lmax, __shfl_down(lmax, off));
  }
  __shared__ float smin[4], smax[4];
  const int lane = threadIdx.x & 63, wv = threadIdx.x >> 6;
  if (lane == 0) { smin[wv] = lmin; smax[wv] = lmax; }
  __syncthreads();
  if (threadIdx.x == 0) {
    const float m1 = fminf(fminf(smin[0], smin[1]), fminf(smin[2], smin[3]));
    const float m2 = fmaxf(fmaxf(smax[0], smax[1]), fmaxf(smax[2], smax[3]));
    atomicMin(&w[0], fmap(m1));
    atomicMax(&w[1], fmap(m2));
  }
}

// One block per image b. Computes MSE partial, EPI sobel partials (batch-smoothing
// folded into load: z = img[b-1] + 2*img[b] + img[b+1], sobel is linear), and
// SSIM map sum (separable 11-tap gaussian, VALID -> 18x18).
__global__ __launch_bounds__(256) void main_kernel(const float* __restrict__ o,
                                                   const float* __restrict__ t,
                                                   float* __restrict__ ws) {
  __shared__ float sx[IMG], sy[IMG], szo[IMG], szt[IMG];
  __shared__ float v[5][504];          // vertical-pass: [field][r*28+j], r in [0,18)
  __shared__ float red[4][NQ];

  const int tid = threadIdx.x;
  const int b = blockIdx.x;
  const int nb = gridDim.x;
  const int bm = (b > 0) ? b - 1 : 0;              // symmetric pad on batch axis
  const int bp = (b < nb - 1) ? b + 1 : nb - 1;

  float mse = 0.f, ssim_s = 0.f;
  float so = 0.f, st_ = 0.f, soo = 0.f, stt = 0.f, sot = 0.f;

  if (tid < IMG / 4) {
    const float4 a  = ((const float4*)(o + (size_t)b  * IMG))[tid];
    const float4 am = ((const float4*)(o + (size_t)bm * IMG))[tid];
    const float4 ap = ((const float4*)(o + (size_t)bp * IMG))[tid];
    const float4 c  = ((const float4*)(t + (size_t)b  * IMG))[tid];
    const float4 cm = ((const float4*)(t + (size_t)bm * IMG))[tid];
    const float4 cp = ((const float4*)(t + (size_t)bp * IMG))[tid];
    ((float4*)sx)[tid] = a;
    ((float4*)sy)[tid] = c;
    float4 z, w;
    z.x = am.x + 2.f*a.x + ap.x;  z.y = am.y + 2.f*a.y + ap.y;
    z.z = am.z + 2.f*a.z + ap.z;  z.w = am.w + 2.f*a.w + ap.w;
    w.x = cm.x + 2.f*c.x + cp.x;  w.y = cm.y + 2.f*c.y + cp.y;
    w.z = cm.z + 2.f*c.z + cp.z;  w.w = cm.w + 2.f*c.w + cp.w;
    ((float4*)szo)[tid] = z;
    ((float4*)szt)[tid] = w;
    float d;
    d = a.x - c.x; mse = fmaf(d, d, mse);
    d = a.y - c.y; mse = fmaf(d, d, mse);
    d = a.z - c.z; mse = fmaf(d, d, mse);
    d = a.w - c.w; mse = fmaf(d, d, mse);
  }
  __syncthreads();

  // ---- Phase A: sobel on combined images -> EPI sums ----
  // sobel2d: d[i][j] = x[i][j+1]-x[i][j-1] (symmetric clamp), then rows [1,2,1].
  for (int p = tid; p < IMG; p += 256) {
    const int i = p / 28;
    const int j = p - i * 28;
    const int rm = (i > 0 ? i - 1 : 0) * 28;
    const int r0 = i * 28;
    const int rp = (i < 27 ? i + 1 : 27) * 28;
    const int jm = (j > 0) ? j - 1 : 0;
    const int jp = (j < 27) ? j + 1 : 27;
    const float eo = (szo[rm + jp] - szo[rm + jm]) + 2.f * (szo[r0 + jp] - szo[r0 + jm])
                   + (szo[rp + jp] - szo[rp + jm]);
    const float et = (szt[rm + jp] - szt[rm + jm]) + 2.f * (szt[r0 + jp] - szt[r0 + jm])
                   + (szt[rp + jp] - szt[rp + jm]);
    so += eo; st_ += et;
    soo = fmaf(eo, eo, soo);
    stt = fmaf(et, et, stt);
    sot = fmaf(eo, et, sot);
  }

  // ---- Phase B: vertical 11-tap gaussian, 3 output rows per task ----
  for (int q = tid; q < 168; q += 256) {       // 6 row-groups * 28 cols
    const int rg = q / 28;
    const int j = q - rg * 28;
    const int r0 = rg * 3;
    float x[13], y[13];
    #pragma unroll
    for (int k = 0; k < 13; k++) {
      x[k] = sx[(r0 + k) * 28 + j];
      y[k] = sy[(r0 + k) * 28 + j];
    }
    #pragma unroll
    for (int rr = 0; rr < 3; rr++) {
      float a1 = 0.f, a2 = 0.f, a3 = 0.f, a4 = 0.f, a5 = 0.f;
      #pragma unroll
      for (int k = 0; k < 11; k++) {
        const float g = GW[k];
        const float xx = x[k + rr], yy = y[k + rr];
        a1 = fmaf(g, xx, a1);
        a2 = fmaf(g, yy, a2);
        const float gx = g * xx;
        a3 = fmaf(gx, xx, a3);
        a4 = fmaf(g * yy, yy, a4);
        a5 = fmaf(gx, yy, a5);
      }
      const int outp = (r0 + rr) * 28 + j;
      v[0][outp] = a1; v[1][outp] = a2; v[2][outp] = a3; v[3][outp] = a4; v[4][outp] = a5;
    }
  }
  __syncthreads();

  // data_range -> C1, C2 (minmax kernel completed earlier on the stream)
  const unsigned* wsu = (const unsigned*)ws;
  const float dr = funmap(wsu[1]) - funmap(wsu[0]);
  const float C1 = (0.01f * dr) * (0.01f * dr);
  const float C2 = (0.03f * dr) * (0.03f * dr);

  // ---- Phase C: horizontal 11-tap gaussian + ssim map, 3 output cols per task ----
  for (int q = tid; q < 108; q += 256) {       // 18 rows * 6 col-groups
    const int r = q / 6;
    const int cg = q - r * 6;
    const int base = r * 28 + cg * 3;
    float t0[13], t1[13], t2[13], t3[13], t4[13];
    #pragma unroll
    for (int k = 0; k < 13; k++) {
      t0[k] = v[0][base + k];
      t1[k] = v[1][base + k];
      t2[k] = v[2][base + k];
      t3[k] = v[3][base + k];
      t4[k] = v[4][base + k];
    }
    #pragma unroll
    for (int cc = 0; cc < 3; cc++) {
      float m1 = 0.f, m2 = 0.f, xx = 0.f, yy = 0.f, xy = 0.f;
      #pragma unroll
      for (int k = 0; k < 11; k++) {
        const float g = GW[k];
        m1 = fmaf(g, t0[k + cc], m1);
        m2 = fmaf(g, t1[k + cc], m2);
        xx = fmaf(g, t2[k + cc], xx);
        yy = fmaf(g, t3[k + cc], yy);
        xy = fmaf(g, t4[k + cc], xy);
      }
      const float m1s = m1 * m1, m2s = m2 * m2, m12 = m1 * m2;
      const float s1 = xx - m1s, s2 = yy - m2s, s12 = xy - m12;
      const float num = (2.f * m12 + C1) * (2.f * s12 + C2);
      const float den = (m1s + m2s + C1) * (s1 + s2 + C2);
      ssim_s += num / den;
    }
  }

  // ---- block reduction of 7 partials -> bucketed atomics ----
  float vals[NQ] = {mse, ssim_s, so, st_, soo, stt, sot};
  #pragma unroll
  for (int q = 0; q < NQ; q++) {
    #pragma unroll
    for (int off = 32; off > 0; off >>= 1)
      vals[q] += __shfl_down(vals[q], off);
  }
  const int lane = tid & 63, wv = tid >> 6;
  if (lane == 0) {
    #pragma unroll
    for (int q = 0; q < NQ; q++) red[wv][q] = vals[q];
  }
  __syncthreads();
  if (tid < NQ) {
    const float s = red[0][tid] + red[1][tid] + red[2][tid] + red[3][tid];
    atomicAdd(ws + 2 + tid * NBUCKET + (b & (NBUCKET - 1)), s);
  }
}

__global__ __launch_bounds__(256) void final_kernel(const float* __restrict__ ws,
                                                    float* __restrict__ out, int B) {
  __shared__ double sred[4][NQ];
  const int tid = threadIdx.x;
  double vals[NQ];
  #pragma unroll
  for (int q = 0; q < NQ; q++) vals[q] = (double)ws[2 + q * NBUCKET + tid];
  #pragma unroll
  for (int q = 0; q < NQ; q++) {
    #pragma unroll
    for (int off = 32; off > 0; off >>= 1)
      vals[q] += __shfl_down(vals[q], off);
  }
  const int lane = tid & 63, wv = tid >> 6;
  if (lane == 0) {
    #pragma unroll
    for (int q = 0; q < NQ; q++) sred[wv][q] = vals[q];
  }
  __syncthreads();
  if (tid == 0) {
    double s[NQ];
    #pragma unroll
    for (int q = 0; q < NQ; q++)
      s[q] = sred[0][q] + sred[1][q] + sred[2][q] + sred[3][q];
    const double N = (double)B * 784.0;
    const double mse  = s[0] / N;
    const double ssim = s[1] / ((double)B * 324.0);
    const double psnr = 10.0 * log10(1.0 / mse);
    const double cov = s[6] - s[2] * s[3] / N;
    const double va  = s[4] - s[2] * s[2] / N;
    const double vb  = s[5] - s[3] * s[3] / N;
    const double epi = cov / sqrt(va * vb);
    const double loss = 1.0 * mse + 0.5 * (1.0 - ssim) + 0.1 * epi + 0.01 * psnr;
    out[0] = (float)loss;
  }
}

extern "C" void kernel_launch(void* const* d_in, const int* in_sizes, int n_in,
                              void* d_out, int out_size, void* d_ws, size_t ws_size,
                              hipStream_t stream) {
  const float* o = (const float*)d_in[0];
  const float* t = (const float*)d_in[1];
  float* out = (float*)d_out;
  float* ws = (float*)d_ws;
  const int B = in_sizes[0] / IMG;
  const int n4 = in_sizes[1] / 4;
  init_kernel<<<(2 + NQ * NBUCKET + 255) / 256, 256, 0, stream>>>((unsigned*)d_ws);
  minmax_kernel<<<1024, 256, 0, stream>>>((const float4*)t, n4, (unsigned*)d_ws);
  main_kernel<<<B, 256, 0, stream>>>(o, t, ws);
  final_kernel<<<1, 256, 0, stream>>>(ws, out, B);
}

// Round 3
// 476.333 us; speedup vs baseline: 1.4072x; 1.4072x over previous
//
#include <hip/hip_runtime.h>
#include <math.h>

static constexpr int IMG = 784;      // 28*28
static constexpr int NQ = 7;         // mse, ssim, so, st, soo, stt, sot
static constexpr int NBUCKET = 256;
static constexpr int RUN = 32;       // images per wave

// Gaussian window WIN=11, SIGMA=1.5, normalized (precomputed in double).
__device__ constexpr float GWF[11] = {
  0.00102838f, 0.00759875f, 0.03600077f, 0.10936070f, 0.21300554f,
  0.26601173f, 0.21300554f, 0.10936070f, 0.03600077f, 0.00759875f, 0.00102838f
};

typedef __fp16 half2v  __attribute__((ext_vector_type(2)));
typedef __fp16 half4v  __attribute__((ext_vector_type(4)));
typedef __fp16 half8v  __attribute__((ext_vector_type(8)));
typedef float  floatx16 __attribute__((ext_vector_type(16)));

union H8  { half2v h2[4]; half8v h8; };
union H4  { half2v h2[2]; half4v h4; };
union F16U { float4 v4[4]; float f[16]; };

#define MFMA(a, b, c) __builtin_amdgcn_mfma_f32_32x32x16_f16((a), (b), (c), 0, 0, 0)

// order-preserving float <-> uint map (for atomic min/max on floats)
__device__ __forceinline__ unsigned fmap(float f) {
  unsigned b = __float_as_uint(f);
  return (b & 0x80000000u) ? ~b : (b | 0x80000000u);
}
__device__ __forceinline__ float funmap(unsigned u) {
  unsigned b = (u & 0x80000000u) ? (u & 0x7fffffffu) : ~u;
  return __uint_as_float(b);
}

// ws layout (32-bit words): [0]=min_u, [1]=max_u, [2 .. 2+NQ*NBUCKET) = float buckets
__global__ __launch_bounds__(256) void init_kernel(unsigned* __restrict__ w) {
  int idx = blockIdx.x * blockDim.x + threadIdx.x;
  if (idx < 2 + NQ * NBUCKET) w[idx] = (idx == 0) ? 0xFFFFFFFFu : 0u;
}

__global__ __launch_bounds__(256) void minmax_kernel(const float4* __restrict__ t,
                                                     int n4, unsigned* __restrict__ w) {
  float lmin = 3.402823466e38f, lmax = -3.402823466e38f;
  const int stride = gridDim.x * blockDim.x;
  for (int i = blockIdx.x * blockDim.x + threadIdx.x; i < n4; i += stride) {
    const float4 x = t[i];
    lmin = fminf(lmin, fminf(fminf(x.x, x.y), fminf(x.z, x.w)));
    lmax = fmaxf(lmax, fmaxf(fmaxf(x.x, x.y), fmaxf(x.z, x.w)));
  }
  #pragma unroll
  for (int off = 32; off > 0; off >>= 1) {
    lmin = fminf(lmin, __shfl_down(lmin, off));
    lmax = fmaxf(lmax, __shfl_down(lmax, off));
  }
  __shared__ float smin[4], smax[4];
  const int lane = threadIdx.x & 63, wv = threadIdx.x >> 6;
  if (lane == 0) { smin[wv] = lmin; smax[wv] = lmax; }
  __syncthreads();
  if (threadIdx.x == 0) {
    const float m1 = fminf(fminf(smin[0], smin[1]), fminf(smin[2], smin[3]));
    const float m2 = fmaxf(fmaxf(smax[0], smax[1]), fmaxf(smax[2], smax[3]));
    atomicMin(&w[0], fmap(m1));
    atomicMax(&w[1], fmap(m2));
  }
}

// Pack C/D-layout fp32 acc (16 regs) into a col-major fp16 column in LDS.
// C/D layout (verified, m74/m101): col = lane&31, row = (reg&3) + 8*(reg>>2) + 4*(lane>>5).
// Regs 4g..4g+3 are rows 8g+4h .. 8g+4h+3 (contiguous) -> one 8B store each.
__device__ __forceinline__ void store_cd(__fp16* col, int h, const floatx16& d) {
  #pragma unroll
  for (int g = 0; g < 4; ++g) {
    H4 q;
    q.h2[0] = __builtin_amdgcn_cvt_pkrtz(d[4*g + 0], d[4*g + 1]);
    q.h2[1] = __builtin_amdgcn_cvt_pkrtz(d[4*g + 2], d[4*g + 3]);
    *reinterpret_cast<half4v*>(col + 8*g + 4*h) = q.h4;
  }
}

// B-fragment read from a col-major fp16 column: lane wants rows k = 16s+8h .. +7 (16B aligned).
__device__ __forceinline__ half8v load_b(const __fp16* col, int s, int h) {
  return *reinterpret_cast<const half8v*>(col + 16*s + 8*h);
}

// One wave per RUN contiguous images. No __syncthreads anywhere: each wave owns
// its LDS slice; cross-lane relayout goes through per-wave LDS (within-wave
// program order). All 28->32 padding is killed by zeros baked into the constant
// fragments, so garbage rows/cols never reach the accumulated sums.
__global__ __launch_bounds__(256, 2) void main_kernel(const float* __restrict__ o,
                                                      const float* __restrict__ t,
                                                      float* __restrict__ ws, int B) {
  // per-wave LDS: H = 5 fields, col-major [18 cols][stride 40 halves] (stride 40:
  // 16B-aligned col base for b128 reads + 8 distinct bank offsets); S = sobel scratch.
  __shared__ __fp16 sH[4][5 * 18 * 40];
  __shared__ __fp16 sS[4][32 * 40];

  const int tid  = threadIdx.x;
  const int wv   = tid >> 6;
  const int lane = tid & 63;
  const int h    = lane >> 5;
  const int n31  = lane & 31;

  __fp16* Hb = sH[wv];
  __fp16* Sb = sS[wv];

  // ---- constant fragments (A layout: m=lane&31,k=8*(lane>>5)+j; B layout: n=lane&31, same k) ----
  // GF: gauss. As B-frag: Gh^T[k][n]=GW[k-n] (n<18, 0<=k-n<=10). As A-frag: Gv[m][k]=GW[k-m]. Identical per-lane.
  // DT: B-frag of D^T (horizontal derivative, symmetric pad): +1 @ k=min(n+1,27), -1 @ k=max(n-1,0); 0 for n>=28.
  // SV: A-frag of Sv (vertical [1,2,1], symmetric pad): 2 @ k=m, +1 @ k=min(m+1,27), +1 @ k=max(m-1,0); 0 for m>=28.
  half8v GF[2], DT[2], SV[2];
  {
    H8 g[2], d[2], sm[2];
    #pragma unroll
    for (int st = 0; st < 2; ++st) {
      #pragma unroll
      for (int jp = 0; jp < 4; ++jp) {
        float gv[2], dv[2], sv[2];
        #pragma unroll
        for (int u = 0; u < 2; ++u) {
          const int k = 16*st + 8*h + 2*jp + u;
          const int i = n31;
          gv[u] = (i < 18 && k >= i && (k - i) <= 10) ? GWF[k - i] : 0.f;
          float dd = 0.f, ss = 0.f;
          if (i < 28) {
            const int kp = (i < 27) ? i + 1 : 27;
            const int km = (i > 0) ? i - 1 : 0;
            dd = ((k == kp) ? 1.f : 0.f) - ((k == km) ? 1.f : 0.f);
            ss = ((k == i) ? 2.f : 0.f) + ((k == kp) ? 1.f : 0.f) + ((k == km) ? 1.f : 0.f);
          }
          dv[u] = dd; sv[u] = ss;
        }
        g[st].h2[jp]  = __builtin_amdgcn_cvt_pkrtz(gv[0], gv[1]);
        d[st].h2[jp]  = __builtin_amdgcn_cvt_pkrtz(dv[0], dv[1]);
        sm[st].h2[jp] = __builtin_amdgcn_cvt_pkrtz(sv[0], sv[1]);
      }
    }
    GF[0] = g[0].h8;  GF[1] = g[1].h8;
    DT[0] = d[0].h8;  DT[1] = d[1].h8;
    SV[0] = sm[0].h8; SV[1] = sm[1].h8;
  }

  const unsigned* wsu = (const unsigned*)ws;
  const float dr = funmap(wsu[1]) - funmap(wsu[0]);
  const float C1 = (0.01f * dr) * (0.01f * dr);
  const float C2 = (0.03f * dr) * (0.03f * dr);

  const int wave_id = blockIdx.x * 4 + wv;
  const int s0 = wave_id * RUN;

  float mse = 0.f, ssim_s = 0.f, so = 0.f, st_ = 0.f, soo = 0.f, stt = 0.f, sot = 0.f;

  if (s0 < B) {
    const int e0 = min(s0 + RUN, B);
    const int row = (n31 < 28) ? n31 : 27;    // clamp dup rows 28-31 (masked everywhere)
    const bool rowok = (n31 < 28);
    // rolling partial batch-smoothed edge maps: e1 = F_{m-1}+2F_m (partial e_m), e2 = F_m
    floatx16 e1o = {}, e2o = {}, e1t = {}, e2t = {};

    for (int m = s0 - 1; m <= e0; ++m) {
      const int mc = (m < 0) ? 0 : ((m >= B) ? (B - 1) : m);  // symmetric batch pad
      const float* po = o + (size_t)mc * IMG + row * 28;
      const float* pt = t + (size_t)mc * IMG + row * 28;

      // lane holds row `row`, 16 cols: step0 = cols 8h..8h+7, step1 = cols 16+8h..16+8h+7
      // (h==1 step1 tail cols 28-31 are zeros; also keeps last-image loads in-bounds)
      F16U X, Y;
      X.v4[0] = *(const float4*)(po + 8*h);
      X.v4[1] = *(const float4*)(po + 8*h + 4);
      X.v4[2] = *(const float4*)(po + 16 + 8*h);
      Y.v4[0] = *(const float4*)(pt + 8*h);
      Y.v4[1] = *(const float4*)(pt + 8*h + 4);
      Y.v4[2] = *(const float4*)(pt + 16 + 8*h);
      if (h == 0) {
        X.v4[3] = *(const float4*)(po + 20);
        Y.v4[3] = *(const float4*)(pt + 20);
      } else {
        X.v4[3] = make_float4(0.f, 0.f, 0.f, 0.f);
        Y.v4[3] = make_float4(0.f, 0.f, 0.f, 0.f);
      }

      const bool inrun = (m >= s0) && (m < e0);

      if (inrun && rowok) {    // fp32 MSE (zero-pad cols cancel: both zero)
        #pragma unroll
        for (int i2 = 0; i2 < 16; ++i2) {
          const float dd = X.f[i2] - Y.f[i2];
          mse = fmaf(dd, dd, mse);
        }
      }

      // A-fragments (fp16): x, y and pointwise x^2, y^2, xy fields
      H8 ax[2], ay[2], axx[2], ayy[2], axy[2];
      #pragma unroll
      for (int st2 = 0; st2 < 2; ++st2) {
        #pragma unroll
        for (int jp = 0; jp < 4; ++jp) {
          const int i0 = 8*st2 + 2*jp;
          const float x0 = X.f[i0], x1 = X.f[i0 + 1];
          const float y0 = Y.f[i0], y1 = Y.f[i0 + 1];
          ax[st2].h2[jp]  = __builtin_amdgcn_cvt_pkrtz(x0, x1);
          ay[st2].h2[jp]  = __builtin_amdgcn_cvt_pkrtz(y0, y1);
          axx[st2].h2[jp] = __builtin_amdgcn_cvt_pkrtz(x0 * x0, x1 * x1);
          ayy[st2].h2[jp] = __builtin_amdgcn_cvt_pkrtz(y0 * y0, y1 * y1);
          axy[st2].h2[jp] = __builtin_amdgcn_cvt_pkrtz(x0 * y0, x1 * y1);
        }
      }

      const floatx16 z16 = {};

      // ---- sobel per image: F = Sv * (X * D^T); C-layout -> B-frag via LDS relayout ----
      __fp16* scol = Sb + n31 * 40;
      floatx16 d1 = MFMA(ax[0].h8, DT[0], z16);
      d1 = MFMA(ax[1].h8, DT[1], d1);
      store_cd(scol, h, d1);
      half8v b0 = load_b(scol, 0, h);
      half8v b1 = load_b(scol, 1, h);
      floatx16 Fxn = MFMA(SV[0], b0, z16);
      Fxn = MFMA(SV[1], b1, Fxn);

      floatx16 d2 = MFMA(ay[0].h8, DT[0], z16);
      d2 = MFMA(ay[1].h8, DT[1], d2);
      store_cd(scol, h, d2);
      b0 = load_b(scol, 0, h);
      b1 = load_b(scol, 1, h);
      floatx16 Ftn = MFMA(SV[0], b0, z16);
      Ftn = MFMA(SV[1], b1, Ftn);

      // ---- EPI: e_{m-1} = F_{m-2} + 2F_{m-1} + F_m completes now ----
      if (m > s0) {
        #pragma unroll
        for (int r = 0; r < 16; ++r) {
          const float eo = e1o[r] + Fxn[r];
          const float et = e1t[r] + Ftn[r];
          so += eo; st_ += et;
          soo = fmaf(eo, eo, soo);
          stt = fmaf(et, et, stt);
          sot = fmaf(eo, et, sot);
        }
      }
      #pragma unroll
      for (int r = 0; r < 16; ++r) {
        e1o[r] = fmaf(2.f, Fxn[r], e2o[r]); e2o[r] = Fxn[r];
        e1t[r] = fmaf(2.f, Ftn[r], e2t[r]); e2t[r] = Ftn[r];
      }

      if (inrun) {
        // ---- pass1: horizontal gauss per field, store transposed (col-major) into H ----
        {
          floatx16 a = MFMA(ax[0].h8, GF[0], z16);  a = MFMA(ax[1].h8, GF[1], a);
          if (n31 < 18) store_cd(Hb + 0*720 + n31*40, h, a);
        }
        {
          floatx16 a = MFMA(ay[0].h8, GF[0], z16);  a = MFMA(ay[1].h8, GF[1], a);
          if (n31 < 18) store_cd(Hb + 1*720 + n31*40, h, a);
        }
        {
          floatx16 a = MFMA(axx[0].h8, GF[0], z16); a = MFMA(axx[1].h8, GF[1], a);
          if (n31 < 18) store_cd(Hb + 2*720 + n31*40, h, a);
        }
        {
          floatx16 a = MFMA(ayy[0].h8, GF[0], z16); a = MFMA(ayy[1].h8, GF[1], a);
          if (n31 < 18) store_cd(Hb + 3*720 + n31*40, h, a);
        }
        {
          floatx16 a = MFMA(axy[0].h8, GF[0], z16); a = MFMA(axy[1].h8, GF[1], a);
          if (n31 < 18) store_cd(Hb + 4*720 + n31*40, h, a);
        }

        // ---- pass2: vertical gauss (A = GF as Gv), B-frags from H ----
        const int cc = (n31 < 18) ? n31 : 17;   // clamp: lanes n>=18 read valid data, masked below
        floatx16 g5[5];
        #pragma unroll
        for (int f = 0; f < 5; ++f) {
          const __fp16* hc = Hb + f*720 + cc*40;
          const half8v hb0 = load_b(hc, 0, h);
          const half8v hb1 = load_b(hc, 1, h);
          floatx16 acc = MFMA(GF[0], hb0, z16);
          acc = MFMA(GF[1], hb1, acc);
          g5[f] = acc;
        }

        // ---- SSIM map + masked accumulation (valid 18x18) ----
        const bool colok = (n31 < 18);
        #pragma unroll
        for (int r = 0; r < 16; ++r) {
          const int rpos = (r & 3) + 8*(r >> 2) + 4*h;
          const float m1 = g5[0][r], m2v = g5[1][r];
          const float xx = g5[2][r], yy = g5[3][r], xy = g5[4][r];
          const float m1s = m1 * m1, m2s = m2v * m2v, m12 = m1 * m2v;
          const float s1v = xx - m1s, s2v = yy - m2s, s12 = xy - m12;
          const float num = fmaf(2.f, m12, C1) * fmaf(2.f, s12, C2);
          const float den = (m1s + m2s + C1) * (s1v + s2v + C2);
          const float val = num * __builtin_amdgcn_rcpf(den);
          ssim_s += (colok && (rpos < 18)) ? val : 0.f;
        }
      }
    }
  }

  // ---- per-wave reduction -> bucketed atomics ----
  float vals[NQ] = {mse, ssim_s, so, st_, soo, stt, sot};
  #pragma unroll
  for (int q = 0; q < NQ; ++q) {
    #pragma unroll
    for (int off = 32; off > 0; off >>= 1)
      vals[q] += __shfl_down(vals[q], off);
  }
  if (lane == 0) {
    #pragma unroll
    for (int q = 0; q < NQ; ++q)
      atomicAdd(ws + 2 + q * NBUCKET + (wave_id & (NBUCKET - 1)), vals[q]);
  }
}

__global__ __launch_bounds__(256) void final_kernel(const float* __restrict__ ws,
                                                    float* __restrict__ out, int B) {
  __shared__ double sred[4][NQ];
  const int tid = threadIdx.x;
  double vals[NQ];
  #pragma unroll
  for (int q = 0; q < NQ; q++) vals[q] = (double)ws[2 + q * NBUCKET + tid];
  #pragma unroll
  for (int q = 0; q < NQ; q++) {
    #pragma unroll
    for (int off = 32; off > 0; off >>= 1)
      vals[q] += __shfl_down(vals[q], off);
  }
  const int lane = tid & 63, wv = tid >> 6;
  if (lane == 0) {
    #pragma unroll
    for (int q = 0; q < NQ; q++) sred[wv][q] = vals[q];
  }
  __syncthreads();
  if (tid == 0) {
    double s[NQ];
    #pragma unroll
    for (int q = 0; q < NQ; q++)
      s[q] = sred[0][q] + sred[1][q] + sred[2][q] + sred[3][q];
    const double N = (double)B * 784.0;
    const double mse  = s[0] / N;
    const double ssim = s[1] / ((double)B * 324.0);
    const double psnr = 10.0 * log10(1.0 / mse);
    const double cov = s[6] - s[2] * s[3] / N;
    const double va  = s[4] - s[2] * s[2] / N;
    const double vb  = s[5] - s[3] * s[3] / N;
    const double epi = cov / sqrt(va * vb);
    const double loss = 1.0 * mse + 0.5 * (1.0 - ssim) + 0.1 * epi + 0.01 * psnr;
    out[0] = (float)loss;
  }
}

extern "C" void kernel_launch(void* const* d_in, const int* in_sizes, int n_in,
                              void* d_out, int out_size, void* d_ws, size_t ws_size,
                              hipStream_t stream) {
  const float* o = (const float*)d_in[0];
  const float* t = (const float*)d_in[1];
  float* out = (float*)d_out;
  float* ws = (float*)d_ws;
  const int B = in_sizes[0] / IMG;
  const int n4 = in_sizes[1] / 4;
  const int nwaves = (B + RUN - 1) / RUN;
  const int grid = (nwaves + 3) / 4;
  init_kernel<<<(2 + NQ * NBUCKET + 255) / 256, 256, 0, stream>>>((unsigned*)d_ws);
  minmax_kernel<<<1024, 256, 0, stream>>>((const float4*)t, n4, (unsigned*)d_ws);
  main_kernel<<<grid, 256, 0, stream>>>(o, t, ws, B);
  final_kernel<<<1, 256, 0, stream>>>(ws, out, B);
}